// Round 1
// baseline (828.348 us; speedup 1.0000x reference)
//
#include <hip/hip_runtime.h>

// Problem constants (from reference)
#define B       4
#define N_CLS   1000
#define SEQ_LEN 77
#define CTX_DIM 512
#define VIS_DIM 512
#define HID     32
#define N_CTX_B 4
#define N_CTX_A 4

#define ROWS      (N_CLS * SEQ_LEN)       // 77000 rows per batch element
#define TASKS     (B * ROWS)              // 308000 (b interleaved fastest)
#define C4        (CTX_DIM / 4)           // 128 float4 per row

// ---------------------------------------------------------------------------
// Kernel 1: bias = relu(im @ w1 + b1) @ w2 + b2   -> ws (4*512 floats)
// Single block, 256 threads. Tiny: ~0.1 MFLOP.
// ---------------------------------------------------------------------------
__global__ __launch_bounds__(256) void mlp_bias_kernel(
    const float* __restrict__ im,    // (4, 512)
    const float* __restrict__ w1,    // (512, 32)
    const float* __restrict__ b1,    // (32)
    const float* __restrict__ w2,    // (32, 512)
    const float* __restrict__ b2,    // (512)
    float* __restrict__ bias_out)    // (4, 512)
{
    __shared__ float s_hid[B][HID];
    const int t = threadIdx.x;

    // Stage A: hidden = relu(im @ w1 + b1); 128 outputs, 1 thread each.
    if (t < B * HID) {
        const int b = t >> 5;          // /32
        const int h = t & 31;
        float acc = 0.0f;
#pragma unroll 8
        for (int v = 0; v < VIS_DIM; ++v)
            acc += im[b * VIS_DIM + v] * w1[v * HID + h];   // w1 read coalesced in h
        acc += b1[h];
        s_hid[b][h] = fmaxf(acc, 0.0f);
    }
    __syncthreads();

    // Stage B: bias = hidden @ w2 + b2; 2048 outputs, 8 per thread.
#pragma unroll
    for (int i = 0; i < 8; ++i) {
        const int idx = t + i * 256;   // 0..2047
        const int b = idx >> 9;        // /512
        const int c = idx & 511;
        float acc = b2[c];
#pragma unroll
        for (int h = 0; h < HID; ++h)
            acc += s_hid[b][h] * w2[h * CTX_DIM + c];       // w2 read coalesced in c
        bias_out[idx] = acc;
    }
}

// ---------------------------------------------------------------------------
// Kernel 2: the big scatter/copy. One float4 per thread, 128 lanes per row.
// Branch is uniform per row (2 waves), so no divergence.
// b is interleaved fastest in the task index so the 4 broadcast readers of
// each embedding row are temporally adjacent (L2/L3 reuse).
// ---------------------------------------------------------------------------
__global__ __launch_bounds__(256) void scatter_kernel(
    const float4* __restrict__ emb,      // (1000, 77, 512) as float4
    const float4* __restrict__ ctxb,     // (4, 512) as float4
    const float4* __restrict__ ctxa,     // (4, 512) as float4
    const int*    __restrict__ name_lens,// (1000)
    const float4* __restrict__ bias,     // (4, 512) as float4 (from ws)
    float4* __restrict__ out)            // (4, 1000, 77, 512) as float4
{
    const int task = blockIdx.x * 2 + (threadIdx.x >> 7);
    if (task >= TASKS) return;
    const int c4  = threadIdx.x & (C4 - 1);
    const int b   = task & (B - 1);      // b fastest -> embedding row reuse
    const int row = task >> 2;           // n*77 + s
    const int n   = row / SEQ_LEN;
    const int s   = row - n * SEQ_LEN;

    float4 val;
    if ((unsigned)(s - 1) < (unsigned)N_CTX_B) {
        // positions 1..4: ctx_beforename[s-1] + bias[b]
        const int j = s - 1;
        const float4 c  = ctxb[j * C4 + c4];
        const float4 bs = bias[b * C4 + c4];
        val = make_float4(c.x + bs.x, c.y + bs.y, c.z + bs.z, c.w + bs.w);
    } else {
        const int sa = 1 + N_CTX_B + name_lens[n];
        if ((unsigned)(s - sa) < (unsigned)N_CTX_A) {
            const int j = s - sa;
            const float4 c  = ctxa[j * C4 + c4];
            const float4 bs = bias[b * C4 + c4];
            val = make_float4(c.x + bs.x, c.y + bs.y, c.z + bs.z, c.w + bs.w);
        } else {
            val = emb[row * C4 + c4];
        }
    }
    out[(size_t)(b * ROWS + row) * C4 + c4] = val;
}

// ---------------------------------------------------------------------------
extern "C" void kernel_launch(void* const* d_in, const int* in_sizes, int n_in,
                              void* d_out, int out_size, void* d_ws, size_t ws_size,
                              hipStream_t stream)
{
    const float* im   = (const float*)d_in[0];  // (4, 512)
    const float* w1   = (const float*)d_in[1];  // (512, 32)
    const float* b1   = (const float*)d_in[2];  // (32)
    const float* w2   = (const float*)d_in[3];  // (32, 512)
    const float* b2   = (const float*)d_in[4];  // (512)
    const float* ctxb = (const float*)d_in[5];  // (4, 512)
    const float* ctxa = (const float*)d_in[6];  // (4, 512)
    const float* emb  = (const float*)d_in[7];  // (1000, 77, 512)
    const int*   nl   = (const int*)d_in[8];    // (1000)
    float* out  = (float*)d_out;
    float* bias = (float*)d_ws;                 // 4*512 floats = 8 KB scratch

    mlp_bias_kernel<<<1, 256, 0, stream>>>(im, w1, b1, w2, b2, bias);

    const int n_blocks = (TASKS + 1) / 2;       // 2 rows (tasks) per 256-thr block
    scatter_kernel<<<n_blocks, 256, 0, stream>>>(
        (const float4*)emb, (const float4*)ctxb, (const float4*)ctxa,
        nl, (const float4*)bias, (float4*)out);
}